// Round 11
// baseline (724.965 us; speedup 1.0000x reference)
//
#include <hip/hip_runtime.h>
#include <cstdint>

#define CH 64
#define NBLK 256          // blocks in bucket passes
#define NBMAX 1024        // max coarse buckets (n <= 131072)
#define SRCMASK 0x1FFFFu  // low 17 bits = src id

typedef __attribute__((ext_vector_type(8))) short bf16x8;
typedef __attribute__((ext_vector_type(8))) unsigned short u16x8;
typedef __attribute__((ext_vector_type(4))) float f32x4;
typedef unsigned int uint32;
typedef unsigned char uchar;

__device__ __forceinline__ unsigned short f2bf(float x) {
  unsigned u = __float_as_uint(x);
  u += 0x7FFF + ((u >> 16) & 1);          // round-to-nearest-even
  return (unsigned short)(u >> 16);
}
__device__ __forceinline__ float bflo(uint32 u) { return __uint_as_float(u << 16); }
__device__ __forceinline__ float bfhi(uint32 u) { return __uint_as_float(u & 0xFFFF0000u); }
__device__ __forceinline__ uint32 bfpack(float lo, float hi) {
  return ((uint32)f2bf(hi) << 16) | (uint32)f2bf(lo);
}

// ---------------- phase 1: per-block LDS histograms of dst>>7 and src>>7 ----------------
__global__ __launch_bounds__(256) void k_b1(const int* __restrict__ src, const int* __restrict__ dst,
                                            int* __restrict__ cntD, int* __restrict__ cntS, int E, int NB) {
  __shared__ int hD[NBMAX], hS[NBMAX];
  int t = threadIdx.x, b = blockIdx.x;
  for (int i = t; i < NBMAX; i += 256) { hD[i] = 0; hS[i] = 0; }
  __syncthreads();
  int chunk = (E + NBLK - 1) / NBLK;
  int e0 = b * chunk, e1 = min(E, e0 + chunk);
  for (int e = e0 + t; e < e1; e += 256) {
    atomicAdd(&hD[dst[e] >> 7], 1);
    atomicAdd(&hS[src[e] >> 7], 1);
  }
  __syncthreads();
  for (int i = t; i < NB; i += 256) {
    cntD[i * NBLK + b] = hD[i];
    cntS[i * NBLK + b] = hS[i];
  }
}

// ---------------- generic 2-level exclusive scan (in-place capable) ----------------
__global__ __launch_bounds__(256) void k_scan_local(const int* __restrict__ in, int* __restrict__ out,
                                                    int* __restrict__ bsum, int total) {
  __shared__ int s[256];
  int t = threadIdx.x;
  int base = blockIdx.x * 1024 + t * 4;
  int v0 = (base + 0 < total) ? in[base + 0] : 0;
  int v1 = (base + 1 < total) ? in[base + 1] : 0;
  int v2 = (base + 2 < total) ? in[base + 2] : 0;
  int v3 = (base + 3 < total) ? in[base + 3] : 0;
  int sum = v0 + v1 + v2 + v3;
  s[t] = sum;
  __syncthreads();
  for (int off = 1; off < 256; off <<= 1) {
    int x = (t >= off) ? s[t - off] : 0;
    __syncthreads();
    s[t] += x;
    __syncthreads();
  }
  int excl = s[t] - sum;
  if (base + 0 < total) out[base + 0] = excl;  excl += v0;
  if (base + 1 < total) out[base + 1] = excl;  excl += v1;
  if (base + 2 < total) out[base + 2] = excl;  excl += v2;
  if (base + 3 < total) out[base + 3] = excl;
  if (t == 255) bsum[blockIdx.x] = s[255];
}

__global__ __launch_bounds__(256) void k_scan_bsums(int* bsum, int nb) {
  __shared__ int s[256];
  int t = threadIdx.x;
  int v = (t < nb) ? bsum[t] : 0;
  s[t] = v;
  __syncthreads();
  for (int off = 1; off < 256; off <<= 1) {
    int x = (t >= off) ? s[t - off] : 0;
    __syncthreads();
    s[t] += x;
    __syncthreads();
  }
  if (t < nb) bsum[t] = s[t] - v;   // exclusive
}

__global__ __launch_bounds__(256) void k_scan_add(int* __restrict__ arr, const int* __restrict__ bsum, int total) {
  int i = blockIdx.x * 256 + threadIdx.x;
  if (i < total) arr[i] += bsum[i >> 10];
}

// ---------------- phase 2: atomic-free scatter into bucket-grouped order ----------------
// etmp record: bits 0-16 = src, bits 17-23 = dst&127 (bucket id gives the rest)
__global__ __launch_bounds__(256) void k_b2(const int* __restrict__ src, const int* __restrict__ dst,
                                            const int* __restrict__ cbaseD, const int* __restrict__ cbaseS,
                                            uint32* __restrict__ etmp, uchar* __restrict__ svals, int E, int NB) {
  __shared__ int curD[NBMAX], curS[NBMAX];
  int t = threadIdx.x, b = blockIdx.x;
  for (int i = t; i < NB; i += 256) {
    curD[i] = cbaseD[i * NBLK + b];
    curS[i] = cbaseS[i * NBLK + b];
  }
  __syncthreads();
  int chunk = (E + NBLK - 1) / NBLK;
  int e0 = b * chunk, e1 = min(E, e0 + chunk);
  for (int e = e0 + t; e < e1; e += 256) {
    int s = src[e], d = dst[e];
    int pd = atomicAdd(&curD[d >> 7], 1);
    etmp[pd] = ((uint32)(d & 127) << 17) | (uint32)s;
    int ps = atomicAdd(&curS[s >> 7], 1);
    svals[ps] = (uchar)(s & 127);
  }
}

// ---------------- phase 3a: exact out-degree per node -> neg_inv ----------------
__global__ __launch_bounds__(256) void k_b3_deg(const uchar* __restrict__ svals, const int* __restrict__ cbaseS,
                                                float* __restrict__ neg_inv, int n, int E, int NB) {
  __shared__ int h[128];
  int t = threadIdx.x, k = blockIdx.x;
  if (t < 128) h[t] = 0;
  __syncthreads();
  int lo = cbaseS[k * NBLK];
  int hi = (k + 1 < NB) ? cbaseS[(k + 1) * NBLK] : E;
  for (int e = lo + t; e < hi; e += 256) atomicAdd(&h[svals[e]], 1);
  __syncthreads();
  if (t < 128) {
    int node = k * 128 + t;
    if (node < n) {
      int c = h[t];
      neg_inv[node] = c > 0 ? (-1.0f / (float)c) : 0.0f;
    }
  }
}

// ---------------- phase 3b: per-bucket counting sort -> erec(int2) + row_ptr ----------------
__global__ __launch_bounds__(256) void k_b3_dst(const uint32* __restrict__ etmp, const int* __restrict__ cbaseD,
                                                const float* __restrict__ neg_inv, int2* __restrict__ erec,
                                                int* __restrict__ row_ptr, int n, int E, int NB) {
  __shared__ int h[128], sc[128], cur[128];
  int t = threadIdx.x, k = blockIdx.x;
  if (t < 128) h[t] = 0;
  __syncthreads();
  int lo = cbaseD[k * NBLK];
  int hi = (k + 1 < NB) ? cbaseD[(k + 1) * NBLK] : E;
  for (int e = lo + t; e < hi; e += 256) atomicAdd(&h[(etmp[e] >> 17) & 127], 1);
  __syncthreads();
  if (t < 128) sc[t] = h[t];
  __syncthreads();
  for (int off = 1; off < 128; off <<= 1) {
    int x = (t < 128 && t >= off) ? sc[t - off] : 0;
    __syncthreads();
    if (t < 128) sc[t] += x;
    __syncthreads();
  }
  if (t < 128) {
    int excl = sc[t] - h[t];
    cur[t] = excl;
    int node = k * 128 + t;
    if (node < n) row_ptr[node] = lo + excl;
  }
  if (k == NB - 1 && t == 0) row_ptr[n] = E;
  __syncthreads();
  for (int e = lo + t; e < hi; e += 256) {
    uint32 r = etmp[e];
    int s = (int)(r & SRCMASK);
    int pos = atomicAdd(&cur[(r >> 17) & 127], 1);
    erec[lo + pos] = make_int2(s, __float_as_int(neg_inv[s]));
  }
}

// ---------------- degree-sorted node permutation (descending in-degree) ----------------
__global__ __launch_bounds__(256) void k_deg_hist(const int* __restrict__ row_ptr, int* __restrict__ hist, int n) {
  __shared__ int h[256];
  int t = threadIdx.x;
  h[t] = 0;
  __syncthreads();
  for (int i = blockIdx.x * 256 + t; i < n; i += gridDim.x * 256) {
    int d = min(row_ptr[i + 1] - row_ptr[i], 255);
    atomicAdd(&h[255 - d], 1);          // reversed bin -> descending degree
  }
  __syncthreads();
  if (h[t]) atomicAdd(&hist[t], h[t]);
}

__global__ __launch_bounds__(256) void k_deg_scan(int* hist) {
  __shared__ int s[256];
  int t = threadIdx.x;
  int v = hist[t];
  s[t] = v;
  __syncthreads();
  for (int off = 1; off < 256; off <<= 1) {
    int x = (t >= off) ? s[t - off] : 0;
    __syncthreads();
    s[t] += x;
    __syncthreads();
  }
  hist[t] = s[t] - v;                   // exclusive
}

__global__ __launch_bounds__(256) void k_deg_scatter(const int* __restrict__ row_ptr, int* __restrict__ hist,
                                                     int* __restrict__ perm, int n) {
  for (int i = blockIdx.x * 256 + threadIdx.x; i < n; i += gridDim.x * 256) {
    int d = min(row_ptr[i + 1] - row_ptr[i], 255);
    int pos = atomicAdd(&hist[255 - d], 1);
    perm[pos] = i;
  }
}

// ---------------- fp32 -> bf16 cast ----------------
__global__ __launch_bounds__(256) void k_cast(const float* __restrict__ x, unsigned short* __restrict__ xb,
                                              int total8) {
  int i = blockIdx.x * 256 + threadIdx.x;
  if (i < total8) {
    const float4* p = (const float4*)(x + (size_t)i * 8);
    float4 v0 = p[0], v1 = p[1];
    u16x8 w;
    w[0] = f2bf(v0.x); w[1] = f2bf(v0.y); w[2] = f2bf(v0.z); w[3] = f2bf(v0.w);
    w[4] = f2bf(v1.x); w[5] = f2bf(v1.y); w[6] = f2bf(v1.z); w[7] = f2bf(v1.w);
    *(u16x8*)(xb + (size_t)i * 8) = w;
  }
}

// ---------------- sparse propagation: HALF-WAVE per node (degree-sorted slots) ----------------
// Lanes 0-31 own node perm[slotA], lanes 32-63 perm[slotB]; lane holds uint = 2 bf16
// channels. 8-deep unroll -> 8 outstanding 256B gathers/wave. Degree-sorted perm makes
// co-resident halves near-equal work (kills max-of-8 Poisson retirement skew).
__global__ __launch_bounds__(256) void k_prop(const int* __restrict__ row_ptr, const int2* __restrict__ erec,
                                              const int* __restrict__ perm,
                                              const uint32* __restrict__ t_in,
                                              const uint32* __restrict__ t_sub,
                                              uint32* __restrict__ t_out, int n, int mode) {
  int tid = threadIdx.x;
  int lane = tid & 63;
  int cp = lane & 31;                    // channel pair: channels 2cp, 2cp+1
  int h = lane >> 5;                     // half id -> which slot
  int slot = blockIdx.x * 8 + ((tid >> 6) << 1) + h;
  bool active = slot < n;
  int node = active ? perm[slot] : 0;
  int beg = active ? row_ptr[node] : 0;
  int end = active ? row_ptr[node + 1] : 0;
  float a0 = 0.f, a1 = 0.f, b0 = 0.f, b1 = 0.f, c0 = 0.f, c1 = 0.f, d0 = 0.f, d1 = 0.f;
  float e0a = 0.f, e1a = 0.f, f0 = 0.f, f1 = 0.f, g0 = 0.f, g1 = 0.f, h0 = 0.f, h1 = 0.f;
  int e = beg;
  for (; e + 8 <= end; e += 8) {
    int2 q0 = erec[e + 0]; int2 q1 = erec[e + 1]; int2 q2 = erec[e + 2]; int2 q3 = erec[e + 3];
    int2 q4 = erec[e + 4]; int2 q5 = erec[e + 5]; int2 q6 = erec[e + 6]; int2 q7 = erec[e + 7];
    uint32 u0 = t_in[q0.x * 32 + cp];
    uint32 u1 = t_in[q1.x * 32 + cp];
    uint32 u2 = t_in[q2.x * 32 + cp];
    uint32 u3 = t_in[q3.x * 32 + cp];
    uint32 u4 = t_in[q4.x * 32 + cp];
    uint32 u5 = t_in[q5.x * 32 + cp];
    uint32 u6 = t_in[q6.x * 32 + cp];
    uint32 u7 = t_in[q7.x * 32 + cp];
    float w0 = __int_as_float(q0.y), w1 = __int_as_float(q1.y);
    float w2 = __int_as_float(q2.y), w3 = __int_as_float(q3.y);
    float w4 = __int_as_float(q4.y), w5 = __int_as_float(q5.y);
    float w6 = __int_as_float(q6.y), w7 = __int_as_float(q7.y);
    a0 = fmaf(w0, bflo(u0), a0);   a1 = fmaf(w0, bfhi(u0), a1);
    b0 = fmaf(w1, bflo(u1), b0);   b1 = fmaf(w1, bfhi(u1), b1);
    c0 = fmaf(w2, bflo(u2), c0);   c1 = fmaf(w2, bfhi(u2), c1);
    d0 = fmaf(w3, bflo(u3), d0);   d1 = fmaf(w3, bfhi(u3), d1);
    e0a = fmaf(w4, bflo(u4), e0a); e1a = fmaf(w4, bfhi(u4), e1a);
    f0 = fmaf(w5, bflo(u5), f0);   f1 = fmaf(w5, bfhi(u5), f1);
    g0 = fmaf(w6, bflo(u6), g0);   g1 = fmaf(w6, bfhi(u6), g1);
    h0 = fmaf(w7, bflo(u7), h0);   h1 = fmaf(w7, bfhi(u7), h1);
  }
  if (e + 4 <= end) {
    int2 q0 = erec[e + 0]; int2 q1 = erec[e + 1]; int2 q2 = erec[e + 2]; int2 q3 = erec[e + 3];
    uint32 u0 = t_in[q0.x * 32 + cp];
    uint32 u1 = t_in[q1.x * 32 + cp];
    uint32 u2 = t_in[q2.x * 32 + cp];
    uint32 u3 = t_in[q3.x * 32 + cp];
    float w0 = __int_as_float(q0.y), w1 = __int_as_float(q1.y);
    float w2 = __int_as_float(q2.y), w3 = __int_as_float(q3.y);
    a0 = fmaf(w0, bflo(u0), a0);   a1 = fmaf(w0, bfhi(u0), a1);
    b0 = fmaf(w1, bflo(u1), b0);   b1 = fmaf(w1, bfhi(u1), b1);
    c0 = fmaf(w2, bflo(u2), c0);   c1 = fmaf(w2, bfhi(u2), c1);
    d0 = fmaf(w3, bflo(u3), d0);   d1 = fmaf(w3, bfhi(u3), d1);
    e += 4;
  }
  if (e + 2 <= end) {
    int2 q0 = erec[e + 0]; int2 q1 = erec[e + 1];
    uint32 u0 = t_in[q0.x * 32 + cp];
    uint32 u1 = t_in[q1.x * 32 + cp];
    float w0 = __int_as_float(q0.y), w1 = __int_as_float(q1.y);
    a0 = fmaf(w0, bflo(u0), a0);   a1 = fmaf(w0, bfhi(u0), a1);
    b0 = fmaf(w1, bflo(u1), b0);   b1 = fmaf(w1, bfhi(u1), b1);
    e += 2;
  }
  if (e < end) {
    int2 q = erec[e];
    uint32 u = t_in[q.x * 32 + cp];
    float w = __int_as_float(q.y);
    a0 = fmaf(w, bflo(u), a0);
    a1 = fmaf(w, bfhi(u), a1);
  }
  float s0 = ((a0 + b0) + (c0 + d0)) + ((e0a + f0) + (g0 + h0));
  float s1 = ((a1 + b1) + (c1 + d1)) + ((e1a + f1) + (g1 + h1));
  if (active) {
    if (mode == 2) {
      uint32 u = t_sub[(size_t)node * 32 + cp];
      s0 = 2.0f * s0 - bflo(u);
      s1 = 2.0f * s1 - bfhi(u);
    }
    t_out[(size_t)node * 32 + cp] = bfpack(s0, s1);
  }
}

// ---------------- W transpose + bf16 convert: Wt[j*320 + k] = bf16(W[k*64 + j]) ----------------
__global__ __launch_bounds__(256) void k_prepW(const float* __restrict__ W, unsigned short* __restrict__ Wt) {
  int o = blockIdx.x * 256 + threadIdx.x;  // o = j*320 + k
  if (o < 64 * 320) {
    int j = o / 320, k = o - j * 320;
    Wt[o] = f2bf(W[k * 64 + j]);
  }
}

__device__ __forceinline__ float selu(float v) {
  const float sc = 1.0507009873554805f, al = 1.6732632423543773f;
  return (v > 0.f) ? (sc * v) : (sc * al * (expf(v) - 1.f));
}

// ---------------- layer-1: 32-row tile, out = selu([M0|..|M4] @ stackedW + b) -> bf16 ----------------
__global__ __launch_bounds__(256) void k_gemm5(
    const unsigned short* __restrict__ M0, const unsigned short* __restrict__ M1,
    const unsigned short* __restrict__ M2, const unsigned short* __restrict__ M3,
    const unsigned short* __restrict__ M4,
    const unsigned short* __restrict__ Wt, const float* __restrict__ bias,
    unsigned short* __restrict__ outp, int n) {
  __shared__ unsigned short lds[32 * 320];  // 20KB, A tile, 16B-chunk XOR swizzle
  const int t = threadIdx.x;
  const int lane = t & 63, wave = t >> 6;
  const int node0 = blockIdx.x * 32;
  const unsigned short* mats[5] = {M0, M1, M2, M3, M4};
#pragma unroll
  for (int m = 0; m < 5; ++m) {
    int row = t >> 3;                     // 0..31
    int cc = t & 7;
    int ca = m * 8 + cc;
    u16x8 w = {};
    if (node0 + row < n)
      w = *(const u16x8*)(mats[m] + (size_t)(node0 + row) * CH + cc * 8);
    *(u16x8*)(&lds[row * 320 + ((ca ^ (row & 7)) << 3)]) = w;
  }
  __syncthreads();
  const int g = lane >> 4, r16 = lane & 15;
  const int rowA0 = r16, rowA1 = r16 + 16;
  const int colB = wave * 16 + r16;
  f32x4 acc0 = {}, acc1 = {};
#pragma unroll 2
  for (int kk = 0; kk < 10; ++kk) {
    int ca = kk * 4 + g;
    bf16x8 a0 = *(const bf16x8*)(&lds[rowA0 * 320 + ((ca ^ (rowA0 & 7)) << 3)]);
    bf16x8 a1 = *(const bf16x8*)(&lds[rowA1 * 320 + ((ca ^ (rowA1 & 7)) << 3)]);
    bf16x8 b = *(const bf16x8*)(Wt + colB * 320 + kk * 32 + g * 8);
    acc0 = __builtin_amdgcn_mfma_f32_16x16x32_bf16(a0, b, acc0, 0, 0, 0);
    acc1 = __builtin_amdgcn_mfma_f32_16x16x32_bf16(a1, b, acc1, 0, 0, 0);
  }
  const f32x4 accs[2] = {acc0, acc1};
  int col = wave * 16 + r16;
  float bv = bias[col];
#pragma unroll
  for (int i = 0; i < 2; ++i) {
#pragma unroll
    for (int rr = 0; rr < 4; ++rr) {
      int row = node0 + i * 16 + g * 4 + rr;
      if (row < n)
        outp[(size_t)row * CH + col] = f2bf(selu(accs[i][rr] + bv));
    }
  }
}

// ---------------- layer-2: 32-row tile gemm + selu + FUSED global_add_pool ----------------
__global__ __launch_bounds__(256) void k_gemm5_pool(
    const unsigned short* __restrict__ M0, const unsigned short* __restrict__ M1,
    const unsigned short* __restrict__ M2, const unsigned short* __restrict__ M3,
    const unsigned short* __restrict__ M4,
    const unsigned short* __restrict__ Wt, const float* __restrict__ bias,
    const int* __restrict__ batch, float* __restrict__ gout, int n) {
  __shared__ unsigned short lds[32 * 320];  // 20KB; reused as float[32][65] in epilogue
  const int t = threadIdx.x;
  const int lane = t & 63, wave = t >> 6;
  const int node0 = blockIdx.x * 32;
  const unsigned short* mats[5] = {M0, M1, M2, M3, M4};
#pragma unroll
  for (int m = 0; m < 5; ++m) {
    int row = t >> 3;
    int cc = t & 7;
    int ca = m * 8 + cc;
    u16x8 w = {};
    if (node0 + row < n)
      w = *(const u16x8*)(mats[m] + (size_t)(node0 + row) * CH + cc * 8);
    *(u16x8*)(&lds[row * 320 + ((ca ^ (row & 7)) << 3)]) = w;
  }
  __syncthreads();
  const int g = lane >> 4, r16 = lane & 15;
  const int rowA0 = r16, rowA1 = r16 + 16;
  const int colB = wave * 16 + r16;
  f32x4 acc0 = {}, acc1 = {};
#pragma unroll 2
  for (int kk = 0; kk < 10; ++kk) {
    int ca = kk * 4 + g;
    bf16x8 a0 = *(const bf16x8*)(&lds[rowA0 * 320 + ((ca ^ (rowA0 & 7)) << 3)]);
    bf16x8 a1 = *(const bf16x8*)(&lds[rowA1 * 320 + ((ca ^ (rowA1 & 7)) << 3)]);
    bf16x8 b = *(const bf16x8*)(Wt + colB * 320 + kk * 32 + g * 8);
    acc0 = __builtin_amdgcn_mfma_f32_16x16x32_bf16(a0, b, acc0, 0, 0, 0);
    acc1 = __builtin_amdgcn_mfma_f32_16x16x32_bf16(a1, b, acc1, 0, 0, 0);
  }
  __syncthreads();                     // all LDS reads done; reuse as float tile
  float* S = (float*)lds;              // [32][65]
  const f32x4 accs[2] = {acc0, acc1};
  {
    int col = wave * 16 + r16;
    float bv = bias[col];
#pragma unroll
    for (int i = 0; i < 2; ++i)
#pragma unroll
      for (int rr = 0; rr < 4; ++rr) {
        int row = i * 16 + g * 4 + rr;
        S[row * 65 + col] = selu(accs[i][rr] + bv);
      }
  }
  __syncthreads();
  // pool: wave w owns rows w*8..w*8+7 (sorted batch -> run-length + atomic flush)
  int c = t & 63, w = t >> 6;
  float cur = 0.f;
  int curg = -1;
  for (int r = 0; r < 8; ++r) {
    int row = w * 8 + r;
    int gn = node0 + row;
    if (gn >= n) break;
    int b = batch[gn];
    if (b != curg) {
      if (curg >= 0) atomicAdd(&gout[curg * CH + c], cur);
      curg = b;
      cur = 0.f;
    }
    cur += S[row * 65 + c];
  }
  if (curg >= 0) atomicAdd(&gout[curg * CH + c], cur);
}

__global__ __launch_bounds__(256) void k_fc(const float* __restrict__ g, const float* __restrict__ Wfc,
                                            const float* __restrict__ bfc, float* __restrict__ outp,
                                            int ng, int oc) {
  int i = blockIdx.x * 256 + threadIdx.x;
  if (i < ng * oc) {
    int gi = i / oc, o = i - gi * oc;
    float s = bfc[o];
    for (int ci = 0; ci < CH; ++ci) s += g[gi * CH + ci] * Wfc[ci * oc + o];
    outp[i] = s;
  }
}

extern "C" void kernel_launch(void* const* d_in, const int* in_sizes, int n_in,
                              void* d_out, int out_size, void* d_ws, size_t ws_size,
                              hipStream_t stream) {
  const float* x   = (const float*)d_in[0];
  const int* eidx  = (const int*)d_in[1];
  const int* batch = (const int*)d_in[2];
  const float* W1  = (const float*)d_in[3];
  const float* b1  = (const float*)d_in[4];
  const float* W2  = (const float*)d_in[5];
  const float* b2  = (const float*)d_in[6];
  const float* Wfc = (const float*)d_in[7];
  const float* bfc = (const float*)d_in[8];
  float* out = (float*)d_out;

  const int n  = in_sizes[0] / CH;        // 100000
  const int E  = in_sizes[1] / 2;         // 1250000
  const int OC = in_sizes[8];             // 10
  const int NG = out_size / OC;           // 64
  const int NB = (n + 127) >> 7;          // 782 coarse buckets

  const int* src = eidx;
  const int* dst = eidx + E;

  size_t off = 0;
  char* base = (char*)d_ws;
  auto alloc = [&](size_t bytes) -> void* {
    size_t cur = (off + 255) & ~(size_t)255;
    off = cur + bytes;
    return (void*)(base + cur);
  };
  const int scan_total = NB * NBLK;                  // 200192
  const int scan_nb    = (scan_total + 1023) / 1024; // 196
  int*   cntD   = (int*)alloc((size_t)scan_total * 4);
  int*   cntS   = (int*)alloc((size_t)scan_total * 4);
  int*   bsumD  = (int*)alloc((size_t)scan_nb * 4);
  int*   bsumS  = (int*)alloc((size_t)scan_nb * 4);
  float* neg_inv = (float*)alloc((size_t)n * 4);
  int*   row_ptr = (int*)alloc((size_t)(n + 1) * 4);
  int2*  erec    = (int2*)alloc((size_t)E * 8);
  int*   perm    = (int*)alloc((size_t)n * 4);
  int*   dhist   = (int*)alloc(256 * 4);
  const size_t tb16 = (size_t)n * CH * 2;
  unsigned short* Xb = (unsigned short*)alloc(tb16);
  unsigned short* T1 = (unsigned short*)alloc(tb16);
  unsigned short* T2 = (unsigned short*)alloc(tb16);
  unsigned short* T3 = (unsigned short*)alloc(tb16);
  unsigned short* T4 = (unsigned short*)alloc(tb16);
  unsigned short* H  = (unsigned short*)alloc(tb16);
  uint32* etmp  = (uint32*)alloc((size_t)E * 4);
  uchar*  svals = (uchar*)alloc((size_t)E);
  float* g  = (float*)alloc((size_t)NG * CH * 4);
  unsigned short* Wt1 = (unsigned short*)alloc(64 * 320 * 2);
  unsigned short* Wt2 = (unsigned short*)alloc(64 * 320 * 2);
  if (off > ws_size) return;  // workspace too small -> fail loudly (zeros out)

  hipMemsetAsync(g, 0, (size_t)NG * CH * 4, stream);
  hipMemsetAsync(dhist, 0, 256 * 4, stream);

  // ---- atomic-free CSR build ----
  k_b1<<<NBLK, 256, 0, stream>>>(src, dst, cntD, cntS, E, NB);
  k_scan_local<<<scan_nb, 256, 0, stream>>>(cntD, cntD, bsumD, scan_total);
  k_scan_bsums<<<1, 256, 0, stream>>>(bsumD, scan_nb);
  k_scan_add<<<(scan_total + 255) / 256, 256, 0, stream>>>(cntD, bsumD, scan_total);
  k_scan_local<<<scan_nb, 256, 0, stream>>>(cntS, cntS, bsumS, scan_total);
  k_scan_bsums<<<1, 256, 0, stream>>>(bsumS, scan_nb);
  k_scan_add<<<(scan_total + 255) / 256, 256, 0, stream>>>(cntS, bsumS, scan_total);
  k_b2<<<NBLK, 256, 0, stream>>>(src, dst, cntD, cntS, etmp, svals, E, NB);
  k_b3_deg<<<NB, 256, 0, stream>>>(svals, cntS, neg_inv, n, E, NB);
  k_b3_dst<<<NB, 256, 0, stream>>>(etmp, cntD, neg_inv, erec, row_ptr, n, E, NB);
  // degree-sorted node permutation (descending)
  k_deg_hist<<<256, 256, 0, stream>>>(row_ptr, dhist, n);
  k_deg_scan<<<1, 256, 0, stream>>>(dhist);
  k_deg_scatter<<<256, 256, 0, stream>>>(row_ptr, dhist, perm, n);

  k_prepW<<<80, 256, 0, stream>>>(W1, Wt1);
  k_prepW<<<80, 256, 0, stream>>>(W2, Wt2);
  k_cast<<<(n * CH / 8 + 255) / 256, 256, 0, stream>>>(x, Xb, n * CH / 8);

  const int pb = (n + 7) / 8;
  const int gb = (n + 31) / 32;
  // layer 1
  k_prop<<<pb, 256, 0, stream>>>(row_ptr, erec, perm, (const uint32*)Xb, nullptr, (uint32*)T1, n, 1);
  k_prop<<<pb, 256, 0, stream>>>(row_ptr, erec, perm, (const uint32*)T1, (const uint32*)Xb, (uint32*)T2, n, 2);
  k_prop<<<pb, 256, 0, stream>>>(row_ptr, erec, perm, (const uint32*)T2, (const uint32*)T1, (uint32*)T3, n, 2);
  k_prop<<<pb, 256, 0, stream>>>(row_ptr, erec, perm, (const uint32*)T3, (const uint32*)T2, (uint32*)T4, n, 2);
  k_gemm5<<<gb, 256, 0, stream>>>(Xb, T1, T2, T3, T4, Wt1, b1, H, n);
  // layer 2: gemm + selu + fused pool -> g
  k_prop<<<pb, 256, 0, stream>>>(row_ptr, erec, perm, (const uint32*)H,  nullptr, (uint32*)T1, n, 1);
  k_prop<<<pb, 256, 0, stream>>>(row_ptr, erec, perm, (const uint32*)T1, (const uint32*)H,  (uint32*)T2, n, 2);
  k_prop<<<pb, 256, 0, stream>>>(row_ptr, erec, perm, (const uint32*)T2, (const uint32*)T1, (uint32*)T3, n, 2);
  k_prop<<<pb, 256, 0, stream>>>(row_ptr, erec, perm, (const uint32*)T3, (const uint32*)T2, (uint32*)T4, n, 2);
  k_gemm5_pool<<<gb, 256, 0, stream>>>(H, T1, T2, T3, T4, Wt2, b2, batch, g, n);
  // fc
  k_fc<<<(NG * OC + 255) / 256, 256, 0, stream>>>(g, Wfc, bfc, out, NG, OC);
}

// Round 12
// 424.707 us; speedup vs baseline: 1.7070x; 1.7070x over previous
//
#include <hip/hip_runtime.h>
#include <cstdint>

#define CH 64
#define NBLK 256          // blocks in bucket passes
#define NBMAX 1024        // max coarse buckets (n <= 131072)
#define SRCMASK 0x1FFFFu  // low 17 bits = src id

typedef __attribute__((ext_vector_type(8))) short bf16x8;
typedef __attribute__((ext_vector_type(8))) unsigned short u16x8;
typedef __attribute__((ext_vector_type(4))) float f32x4;
typedef unsigned int uint32;
typedef unsigned char uchar;

__device__ __forceinline__ unsigned short f2bf(float x) {
  unsigned u = __float_as_uint(x);
  u += 0x7FFF + ((u >> 16) & 1);          // round-to-nearest-even
  return (unsigned short)(u >> 16);
}
__device__ __forceinline__ float bflo(uint32 u) { return __uint_as_float(u << 16); }
__device__ __forceinline__ float bfhi(uint32 u) { return __uint_as_float(u & 0xFFFF0000u); }
__device__ __forceinline__ uint32 bfpack(float lo, float hi) {
  return ((uint32)f2bf(hi) << 16) | (uint32)f2bf(lo);
}

// ---------------- phase 1: per-block LDS histograms of dst>>7 and src>>7 ----------------
__global__ __launch_bounds__(256) void k_b1(const int* __restrict__ src, const int* __restrict__ dst,
                                            int* __restrict__ cntD, int* __restrict__ cntS, int E, int NB) {
  __shared__ int hD[NBMAX], hS[NBMAX];
  int t = threadIdx.x, b = blockIdx.x;
  for (int i = t; i < NBMAX; i += 256) { hD[i] = 0; hS[i] = 0; }
  __syncthreads();
  int chunk = (E + NBLK - 1) / NBLK;
  int e0 = b * chunk, e1 = min(E, e0 + chunk);
  for (int e = e0 + t; e < e1; e += 256) {
    atomicAdd(&hD[dst[e] >> 7], 1);
    atomicAdd(&hS[src[e] >> 7], 1);
  }
  __syncthreads();
  for (int i = t; i < NB; i += 256) {
    cntD[i * NBLK + b] = hD[i];
    cntS[i * NBLK + b] = hS[i];
  }
}

// ---------------- generic 2-level exclusive scan (in-place capable) ----------------
__global__ __launch_bounds__(256) void k_scan_local(const int* __restrict__ in, int* __restrict__ out,
                                                    int* __restrict__ bsum, int total) {
  __shared__ int s[256];
  int t = threadIdx.x;
  int base = blockIdx.x * 1024 + t * 4;
  int v0 = (base + 0 < total) ? in[base + 0] : 0;
  int v1 = (base + 1 < total) ? in[base + 1] : 0;
  int v2 = (base + 2 < total) ? in[base + 2] : 0;
  int v3 = (base + 3 < total) ? in[base + 3] : 0;
  int sum = v0 + v1 + v2 + v3;
  s[t] = sum;
  __syncthreads();
  for (int off = 1; off < 256; off <<= 1) {
    int x = (t >= off) ? s[t - off] : 0;
    __syncthreads();
    s[t] += x;
    __syncthreads();
  }
  int excl = s[t] - sum;
  if (base + 0 < total) out[base + 0] = excl;  excl += v0;
  if (base + 1 < total) out[base + 1] = excl;  excl += v1;
  if (base + 2 < total) out[base + 2] = excl;  excl += v2;
  if (base + 3 < total) out[base + 3] = excl;
  if (t == 255) bsum[blockIdx.x] = s[255];
}

__global__ __launch_bounds__(256) void k_scan_bsums(int* bsum, int nb) {
  __shared__ int s[256];
  int t = threadIdx.x;
  int v = (t < nb) ? bsum[t] : 0;
  s[t] = v;
  __syncthreads();
  for (int off = 1; off < 256; off <<= 1) {
    int x = (t >= off) ? s[t - off] : 0;
    __syncthreads();
    s[t] += x;
    __syncthreads();
  }
  if (t < nb) bsum[t] = s[t] - v;   // exclusive
}

__global__ __launch_bounds__(256) void k_scan_add(int* __restrict__ arr, const int* __restrict__ bsum, int total) {
  int i = blockIdx.x * 256 + threadIdx.x;
  if (i < total) arr[i] += bsum[i >> 10];
}

// ---------------- phase 2: atomic-free scatter into bucket-grouped order ----------------
// etmp record: bits 0-16 = src, bits 17-23 = dst&127 (bucket id gives the rest)
__global__ __launch_bounds__(256) void k_b2(const int* __restrict__ src, const int* __restrict__ dst,
                                            const int* __restrict__ cbaseD, const int* __restrict__ cbaseS,
                                            uint32* __restrict__ etmp, uchar* __restrict__ svals, int E, int NB) {
  __shared__ int curD[NBMAX], curS[NBMAX];
  int t = threadIdx.x, b = blockIdx.x;
  for (int i = t; i < NB; i += 256) {
    curD[i] = cbaseD[i * NBLK + b];
    curS[i] = cbaseS[i * NBLK + b];
  }
  __syncthreads();
  int chunk = (E + NBLK - 1) / NBLK;
  int e0 = b * chunk, e1 = min(E, e0 + chunk);
  for (int e = e0 + t; e < e1; e += 256) {
    int s = src[e], d = dst[e];
    int pd = atomicAdd(&curD[d >> 7], 1);
    etmp[pd] = ((uint32)(d & 127) << 17) | (uint32)s;
    int ps = atomicAdd(&curS[s >> 7], 1);
    svals[ps] = (uchar)(s & 127);
  }
}

// ---------------- phase 3a: exact out-degree per node -> neg_inv ----------------
__global__ __launch_bounds__(256) void k_b3_deg(const uchar* __restrict__ svals, const int* __restrict__ cbaseS,
                                                float* __restrict__ neg_inv, int n, int E, int NB) {
  __shared__ int h[128];
  int t = threadIdx.x, k = blockIdx.x;
  if (t < 128) h[t] = 0;
  __syncthreads();
  int lo = cbaseS[k * NBLK];
  int hi = (k + 1 < NB) ? cbaseS[(k + 1) * NBLK] : E;
  for (int e = lo + t; e < hi; e += 256) atomicAdd(&h[svals[e]], 1);
  __syncthreads();
  if (t < 128) {
    int node = k * 128 + t;
    if (node < n) {
      int c = h[t];
      neg_inv[node] = c > 0 ? (-1.0f / (float)c) : 0.0f;
    }
  }
}

// ---------------- phase 3b: per-bucket counting sort -> erec(int2) + row_ptr ----------------
__global__ __launch_bounds__(256) void k_b3_dst(const uint32* __restrict__ etmp, const int* __restrict__ cbaseD,
                                                const float* __restrict__ neg_inv, int2* __restrict__ erec,
                                                int* __restrict__ row_ptr, int n, int E, int NB) {
  __shared__ int h[128], sc[128], cur[128];
  int t = threadIdx.x, k = blockIdx.x;
  if (t < 128) h[t] = 0;
  __syncthreads();
  int lo = cbaseD[k * NBLK];
  int hi = (k + 1 < NB) ? cbaseD[(k + 1) * NBLK] : E;
  for (int e = lo + t; e < hi; e += 256) atomicAdd(&h[(etmp[e] >> 17) & 127], 1);
  __syncthreads();
  if (t < 128) sc[t] = h[t];
  __syncthreads();
  for (int off = 1; off < 128; off <<= 1) {
    int x = (t < 128 && t >= off) ? sc[t - off] : 0;
    __syncthreads();
    if (t < 128) sc[t] += x;
    __syncthreads();
  }
  if (t < 128) {
    int excl = sc[t] - h[t];
    cur[t] = excl;
    int node = k * 128 + t;
    if (node < n) row_ptr[node] = lo + excl;
  }
  if (k == NB - 1 && t == 0) row_ptr[n] = E;
  __syncthreads();
  for (int e = lo + t; e < hi; e += 256) {
    uint32 r = etmp[e];
    int s = (int)(r & SRCMASK);
    int pos = atomicAdd(&cur[(r >> 17) & 127], 1);
    erec[lo + pos] = make_int2(s, __float_as_int(neg_inv[s]));
  }
}

// ---------------- segmented degree sort: block sorts its 1024-node segment (LDS only) ----------------
__global__ __launch_bounds__(256) void k_deg_seg(const int* __restrict__ row_ptr, int* __restrict__ perm, int n) {
  __shared__ int h[256], cur[256], s[256];
  int t = threadIdx.x;
  int base = blockIdx.x * 1024;
  int lim = min(n - base, 1024);
  h[t] = 0;
  __syncthreads();
  int d[4];
  for (int i = 0; i < 4; ++i) {
    int j = t * 4 + i;
    if (j < lim) {
      int node = base + j;
      d[i] = 255 - min(row_ptr[node + 1] - row_ptr[node], 255);  // reversed -> descending
      atomicAdd(&h[d[i]], 1);
    } else d[i] = -1;
  }
  __syncthreads();
  int v = h[t];
  s[t] = v;
  __syncthreads();
  for (int off = 1; off < 256; off <<= 1) {
    int x = (t >= off) ? s[t - off] : 0;
    __syncthreads();
    s[t] += x;
    __syncthreads();
  }
  cur[t] = s[t] - v;
  __syncthreads();
  for (int i = 0; i < 4; ++i) {
    if (d[i] >= 0) {
      int pos = atomicAdd(&cur[d[i]], 1);
      perm[base + pos] = base + t * 4 + i;
    }
  }
}

// ---------------- fp32 -> bf16 cast ----------------
__global__ __launch_bounds__(256) void k_cast(const float* __restrict__ x, unsigned short* __restrict__ xb,
                                              int total8) {
  int i = blockIdx.x * 256 + threadIdx.x;
  if (i < total8) {
    const float4* p = (const float4*)(x + (size_t)i * 8);
    float4 v0 = p[0], v1 = p[1];
    u16x8 w;
    w[0] = f2bf(v0.x); w[1] = f2bf(v0.y); w[2] = f2bf(v0.z); w[3] = f2bf(v0.w);
    w[4] = f2bf(v1.x); w[5] = f2bf(v1.y); w[6] = f2bf(v1.z); w[7] = f2bf(v1.w);
    *(u16x8*)(xb + (size_t)i * 8) = w;
  }
}

// ---------------- sparse propagation: HALF-WAVE per node (degree-sorted slots) ----------------
__global__ __launch_bounds__(256) void k_prop(const int* __restrict__ row_ptr, const int2* __restrict__ erec,
                                              const int* __restrict__ perm,
                                              const uint32* __restrict__ t_in,
                                              const uint32* __restrict__ t_sub,
                                              uint32* __restrict__ t_out, int n, int mode) {
  int tid = threadIdx.x;
  int lane = tid & 63;
  int cp = lane & 31;                    // channel pair: channels 2cp, 2cp+1
  int h = lane >> 5;                     // half id -> which slot
  int slot = blockIdx.x * 8 + ((tid >> 6) << 1) + h;
  bool active = slot < n;
  int node = active ? perm[slot] : 0;
  int beg = active ? row_ptr[node] : 0;
  int end = active ? row_ptr[node + 1] : 0;
  float a0 = 0.f, a1 = 0.f, b0 = 0.f, b1 = 0.f, c0 = 0.f, c1 = 0.f, d0 = 0.f, d1 = 0.f;
  float e0a = 0.f, e1a = 0.f, f0 = 0.f, f1 = 0.f, g0 = 0.f, g1 = 0.f, h0 = 0.f, h1 = 0.f;
  int e = beg;
  for (; e + 8 <= end; e += 8) {
    int2 q0 = erec[e + 0]; int2 q1 = erec[e + 1]; int2 q2 = erec[e + 2]; int2 q3 = erec[e + 3];
    int2 q4 = erec[e + 4]; int2 q5 = erec[e + 5]; int2 q6 = erec[e + 6]; int2 q7 = erec[e + 7];
    uint32 u0 = t_in[q0.x * 32 + cp];
    uint32 u1 = t_in[q1.x * 32 + cp];
    uint32 u2 = t_in[q2.x * 32 + cp];
    uint32 u3 = t_in[q3.x * 32 + cp];
    uint32 u4 = t_in[q4.x * 32 + cp];
    uint32 u5 = t_in[q5.x * 32 + cp];
    uint32 u6 = t_in[q6.x * 32 + cp];
    uint32 u7 = t_in[q7.x * 32 + cp];
    float w0 = __int_as_float(q0.y), w1 = __int_as_float(q1.y);
    float w2 = __int_as_float(q2.y), w3 = __int_as_float(q3.y);
    float w4 = __int_as_float(q4.y), w5 = __int_as_float(q5.y);
    float w6 = __int_as_float(q6.y), w7 = __int_as_float(q7.y);
    a0 = fmaf(w0, bflo(u0), a0);   a1 = fmaf(w0, bfhi(u0), a1);
    b0 = fmaf(w1, bflo(u1), b0);   b1 = fmaf(w1, bfhi(u1), b1);
    c0 = fmaf(w2, bflo(u2), c0);   c1 = fmaf(w2, bfhi(u2), c1);
    d0 = fmaf(w3, bflo(u3), d0);   d1 = fmaf(w3, bfhi(u3), d1);
    e0a = fmaf(w4, bflo(u4), e0a); e1a = fmaf(w4, bfhi(u4), e1a);
    f0 = fmaf(w5, bflo(u5), f0);   f1 = fmaf(w5, bfhi(u5), f1);
    g0 = fmaf(w6, bflo(u6), g0);   g1 = fmaf(w6, bfhi(u6), g1);
    h0 = fmaf(w7, bflo(u7), h0);   h1 = fmaf(w7, bfhi(u7), h1);
  }
  if (e + 4 <= end) {
    int2 q0 = erec[e + 0]; int2 q1 = erec[e + 1]; int2 q2 = erec[e + 2]; int2 q3 = erec[e + 3];
    uint32 u0 = t_in[q0.x * 32 + cp];
    uint32 u1 = t_in[q1.x * 32 + cp];
    uint32 u2 = t_in[q2.x * 32 + cp];
    uint32 u3 = t_in[q3.x * 32 + cp];
    float w0 = __int_as_float(q0.y), w1 = __int_as_float(q1.y);
    float w2 = __int_as_float(q2.y), w3 = __int_as_float(q3.y);
    a0 = fmaf(w0, bflo(u0), a0);   a1 = fmaf(w0, bfhi(u0), a1);
    b0 = fmaf(w1, bflo(u1), b0);   b1 = fmaf(w1, bfhi(u1), b1);
    c0 = fmaf(w2, bflo(u2), c0);   c1 = fmaf(w2, bfhi(u2), c1);
    d0 = fmaf(w3, bflo(u3), d0);   d1 = fmaf(w3, bfhi(u3), d1);
    e += 4;
  }
  if (e + 2 <= end) {
    int2 q0 = erec[e + 0]; int2 q1 = erec[e + 1];
    uint32 u0 = t_in[q0.x * 32 + cp];
    uint32 u1 = t_in[q1.x * 32 + cp];
    float w0 = __int_as_float(q0.y), w1 = __int_as_float(q1.y);
    a0 = fmaf(w0, bflo(u0), a0);   a1 = fmaf(w0, bfhi(u0), a1);
    b0 = fmaf(w1, bflo(u1), b0);   b1 = fmaf(w1, bfhi(u1), b1);
    e += 2;
  }
  if (e < end) {
    int2 q = erec[e];
    uint32 u = t_in[q.x * 32 + cp];
    float w = __int_as_float(q.y);
    a0 = fmaf(w, bflo(u), a0);
    a1 = fmaf(w, bfhi(u), a1);
  }
  float s0 = ((a0 + b0) + (c0 + d0)) + ((e0a + f0) + (g0 + h0));
  float s1 = ((a1 + b1) + (c1 + d1)) + ((e1a + f1) + (g1 + h1));
  if (active) {
    if (mode == 2) {
      uint32 u = t_sub[(size_t)node * 32 + cp];
      s0 = 2.0f * s0 - bflo(u);
      s1 = 2.0f * s1 - bfhi(u);
    }
    t_out[(size_t)node * 32 + cp] = bfpack(s0, s1);
  }
}

// ---------------- W transpose + bf16 convert: Wt[j*320 + k] = bf16(W[k*64 + j]) ----------------
__global__ __launch_bounds__(256) void k_prepW(const float* __restrict__ W, unsigned short* __restrict__ Wt) {
  int o = blockIdx.x * 256 + threadIdx.x;  // o = j*320 + k
  if (o < 64 * 320) {
    int j = o / 320, k = o - j * 320;
    Wt[o] = f2bf(W[k * 64 + j]);
  }
}

__device__ __forceinline__ float selu(float v) {
  const float sc = 1.0507009873554805f, al = 1.6732632423543773f;
  return (v > 0.f) ? (sc * v) : (sc * al * (expf(v) - 1.f));
}

// ---------------- layer-1: 32-row tile, out = selu([M0|..|M4] @ stackedW + b) -> bf16 ----------------
__global__ __launch_bounds__(256) void k_gemm5(
    const unsigned short* __restrict__ M0, const unsigned short* __restrict__ M1,
    const unsigned short* __restrict__ M2, const unsigned short* __restrict__ M3,
    const unsigned short* __restrict__ M4,
    const unsigned short* __restrict__ Wt, const float* __restrict__ bias,
    unsigned short* __restrict__ outp, int n) {
  __shared__ unsigned short lds[32 * 320];  // 20KB, A tile, 16B-chunk XOR swizzle
  const int t = threadIdx.x;
  const int lane = t & 63, wave = t >> 6;
  const int node0 = blockIdx.x * 32;
  const unsigned short* mats[5] = {M0, M1, M2, M3, M4};
#pragma unroll
  for (int m = 0; m < 5; ++m) {
    int row = t >> 3;                     // 0..31
    int cc = t & 7;
    int ca = m * 8 + cc;
    u16x8 w = {};
    if (node0 + row < n)
      w = *(const u16x8*)(mats[m] + (size_t)(node0 + row) * CH + cc * 8);
    *(u16x8*)(&lds[row * 320 + ((ca ^ (row & 7)) << 3)]) = w;
  }
  __syncthreads();
  const int g = lane >> 4, r16 = lane & 15;
  const int rowA0 = r16, rowA1 = r16 + 16;
  const int colB = wave * 16 + r16;
  f32x4 acc0 = {}, acc1 = {};
#pragma unroll 2
  for (int kk = 0; kk < 10; ++kk) {
    int ca = kk * 4 + g;
    bf16x8 a0 = *(const bf16x8*)(&lds[rowA0 * 320 + ((ca ^ (rowA0 & 7)) << 3)]);
    bf16x8 a1 = *(const bf16x8*)(&lds[rowA1 * 320 + ((ca ^ (rowA1 & 7)) << 3)]);
    bf16x8 b = *(const bf16x8*)(Wt + colB * 320 + kk * 32 + g * 8);
    acc0 = __builtin_amdgcn_mfma_f32_16x16x32_bf16(a0, b, acc0, 0, 0, 0);
    acc1 = __builtin_amdgcn_mfma_f32_16x16x32_bf16(a1, b, acc1, 0, 0, 0);
  }
  const f32x4 accs[2] = {acc0, acc1};
  int col = wave * 16 + r16;
  float bv = bias[col];
#pragma unroll
  for (int i = 0; i < 2; ++i) {
#pragma unroll
    for (int rr = 0; rr < 4; ++rr) {
      int row = node0 + i * 16 + g * 4 + rr;
      if (row < n)
        outp[(size_t)row * CH + col] = f2bf(selu(accs[i][rr] + bv));
    }
  }
}

// ---------------- layer-2: 32-row tile gemm + selu + FUSED global_add_pool ----------------
__global__ __launch_bounds__(256) void k_gemm5_pool(
    const unsigned short* __restrict__ M0, const unsigned short* __restrict__ M1,
    const unsigned short* __restrict__ M2, const unsigned short* __restrict__ M3,
    const unsigned short* __restrict__ M4,
    const unsigned short* __restrict__ Wt, const float* __restrict__ bias,
    const int* __restrict__ batch, float* __restrict__ gout, int n) {
  __shared__ unsigned short lds[32 * 320];  // 20KB; reused as float[32][65] in epilogue
  const int t = threadIdx.x;
  const int lane = t & 63, wave = t >> 6;
  const int node0 = blockIdx.x * 32;
  const unsigned short* mats[5] = {M0, M1, M2, M3, M4};
#pragma unroll
  for (int m = 0; m < 5; ++m) {
    int row = t >> 3;
    int cc = t & 7;
    int ca = m * 8 + cc;
    u16x8 w = {};
    if (node0 + row < n)
      w = *(const u16x8*)(mats[m] + (size_t)(node0 + row) * CH + cc * 8);
    *(u16x8*)(&lds[row * 320 + ((ca ^ (row & 7)) << 3)]) = w;
  }
  __syncthreads();
  const int g = lane >> 4, r16 = lane & 15;
  const int rowA0 = r16, rowA1 = r16 + 16;
  const int colB = wave * 16 + r16;
  f32x4 acc0 = {}, acc1 = {};
#pragma unroll 2
  for (int kk = 0; kk < 10; ++kk) {
    int ca = kk * 4 + g;
    bf16x8 a0 = *(const bf16x8*)(&lds[rowA0 * 320 + ((ca ^ (rowA0 & 7)) << 3)]);
    bf16x8 a1 = *(const bf16x8*)(&lds[rowA1 * 320 + ((ca ^ (rowA1 & 7)) << 3)]);
    bf16x8 b = *(const bf16x8*)(Wt + colB * 320 + kk * 32 + g * 8);
    acc0 = __builtin_amdgcn_mfma_f32_16x16x32_bf16(a0, b, acc0, 0, 0, 0);
    acc1 = __builtin_amdgcn_mfma_f32_16x16x32_bf16(a1, b, acc1, 0, 0, 0);
  }
  __syncthreads();                     // all LDS reads done; reuse as float tile
  float* S = (float*)lds;              // [32][65]
  const f32x4 accs[2] = {acc0, acc1};
  {
    int col = wave * 16 + r16;
    float bv = bias[col];
#pragma unroll
    for (int i = 0; i < 2; ++i)
#pragma unroll
      for (int rr = 0; rr < 4; ++rr) {
        int row = i * 16 + g * 4 + rr;
        S[row * 65 + col] = selu(accs[i][rr] + bv);
      }
  }
  __syncthreads();
  // pool: wave w owns rows w*8..w*8+7 (sorted batch -> run-length + atomic flush)
  int c = t & 63, w = t >> 6;
  float cur = 0.f;
  int curg = -1;
  for (int r = 0; r < 8; ++r) {
    int row = w * 8 + r;
    int gn = node0 + row;
    if (gn >= n) break;
    int b = batch[gn];
    if (b != curg) {
      if (curg >= 0) atomicAdd(&gout[curg * CH + c], cur);
      curg = b;
      cur = 0.f;
    }
    cur += S[row * 65 + c];
  }
  if (curg >= 0) atomicAdd(&gout[curg * CH + c], cur);
}

__global__ __launch_bounds__(256) void k_fc(const float* __restrict__ g, const float* __restrict__ Wfc,
                                            const float* __restrict__ bfc, float* __restrict__ outp,
                                            int ng, int oc) {
  int i = blockIdx.x * 256 + threadIdx.x;
  if (i < ng * oc) {
    int gi = i / oc, o = i - gi * oc;
    float s = bfc[o];
    for (int ci = 0; ci < CH; ++ci) s += g[gi * CH + ci] * Wfc[ci * oc + o];
    outp[i] = s;
  }
}

extern "C" void kernel_launch(void* const* d_in, const int* in_sizes, int n_in,
                              void* d_out, int out_size, void* d_ws, size_t ws_size,
                              hipStream_t stream) {
  const float* x   = (const float*)d_in[0];
  const int* eidx  = (const int*)d_in[1];
  const int* batch = (const int*)d_in[2];
  const float* W1  = (const float*)d_in[3];
  const float* b1  = (const float*)d_in[4];
  const float* W2  = (const float*)d_in[5];
  const float* b2  = (const float*)d_in[6];
  const float* Wfc = (const float*)d_in[7];
  const float* bfc = (const float*)d_in[8];
  float* out = (float*)d_out;

  const int n  = in_sizes[0] / CH;        // 100000
  const int E  = in_sizes[1] / 2;         // 1250000
  const int OC = in_sizes[8];             // 10
  const int NG = out_size / OC;           // 64
  const int NB = (n + 127) >> 7;          // 782 coarse buckets

  const int* src = eidx;
  const int* dst = eidx + E;

  size_t off = 0;
  char* base = (char*)d_ws;
  auto alloc = [&](size_t bytes) -> void* {
    size_t cur = (off + 255) & ~(size_t)255;
    off = cur + bytes;
    return (void*)(base + cur);
  };
  const int scan_total = NB * NBLK;                  // 200192
  const int scan_nb    = (scan_total + 1023) / 1024; // 196
  int*   cntD   = (int*)alloc((size_t)scan_total * 4);
  int*   cntS   = (int*)alloc((size_t)scan_total * 4);
  int*   bsumD  = (int*)alloc((size_t)scan_nb * 4);
  int*   bsumS  = (int*)alloc((size_t)scan_nb * 4);
  float* neg_inv = (float*)alloc((size_t)n * 4);
  int*   row_ptr = (int*)alloc((size_t)(n + 1) * 4);
  int2*  erec    = (int2*)alloc((size_t)E * 8);
  int*   perm    = (int*)alloc((size_t)n * 4);
  const size_t tb16 = (size_t)n * CH * 2;
  unsigned short* Xb = (unsigned short*)alloc(tb16);
  unsigned short* T1 = (unsigned short*)alloc(tb16);
  unsigned short* T2 = (unsigned short*)alloc(tb16);
  unsigned short* T3 = (unsigned short*)alloc(tb16);
  unsigned short* T4 = (unsigned short*)alloc(tb16);
  unsigned short* H  = (unsigned short*)alloc(tb16);
  uint32* etmp  = (uint32*)alloc((size_t)E * 4);
  uchar*  svals = (uchar*)alloc((size_t)E);
  float* g  = (float*)alloc((size_t)NG * CH * 4);
  unsigned short* Wt1 = (unsigned short*)alloc(64 * 320 * 2);
  unsigned short* Wt2 = (unsigned short*)alloc(64 * 320 * 2);
  if (off > ws_size) return;  // workspace too small -> fail loudly (zeros out)

  hipMemsetAsync(g, 0, (size_t)NG * CH * 4, stream);

  // ---- atomic-free CSR build ----
  k_b1<<<NBLK, 256, 0, stream>>>(src, dst, cntD, cntS, E, NB);
  k_scan_local<<<scan_nb, 256, 0, stream>>>(cntD, cntD, bsumD, scan_total);
  k_scan_bsums<<<1, 256, 0, stream>>>(bsumD, scan_nb);
  k_scan_add<<<(scan_total + 255) / 256, 256, 0, stream>>>(cntD, bsumD, scan_total);
  k_scan_local<<<scan_nb, 256, 0, stream>>>(cntS, cntS, bsumS, scan_total);
  k_scan_bsums<<<1, 256, 0, stream>>>(bsumS, scan_nb);
  k_scan_add<<<(scan_total + 255) / 256, 256, 0, stream>>>(cntS, bsumS, scan_total);
  k_b2<<<NBLK, 256, 0, stream>>>(src, dst, cntD, cntS, etmp, svals, E, NB);
  k_b3_deg<<<NB, 256, 0, stream>>>(svals, cntS, neg_inv, n, E, NB);
  k_b3_dst<<<NB, 256, 0, stream>>>(etmp, cntD, neg_inv, erec, row_ptr, n, E, NB);
  // segmented degree sort (per-1024-node, LDS-only atomics)
  k_deg_seg<<<(n + 1023) / 1024, 256, 0, stream>>>(row_ptr, perm, n);

  k_prepW<<<80, 256, 0, stream>>>(W1, Wt1);
  k_prepW<<<80, 256, 0, stream>>>(W2, Wt2);
  k_cast<<<(n * CH / 8 + 255) / 256, 256, 0, stream>>>(x, Xb, n * CH / 8);

  const int pb = (n + 7) / 8;
  const int gb = (n + 31) / 32;
  // layer 1
  k_prop<<<pb, 256, 0, stream>>>(row_ptr, erec, perm, (const uint32*)Xb, nullptr, (uint32*)T1, n, 1);
  k_prop<<<pb, 256, 0, stream>>>(row_ptr, erec, perm, (const uint32*)T1, (const uint32*)Xb, (uint32*)T2, n, 2);
  k_prop<<<pb, 256, 0, stream>>>(row_ptr, erec, perm, (const uint32*)T2, (const uint32*)T1, (uint32*)T3, n, 2);
  k_prop<<<pb, 256, 0, stream>>>(row_ptr, erec, perm, (const uint32*)T3, (const uint32*)T2, (uint32*)T4, n, 2);
  k_gemm5<<<gb, 256, 0, stream>>>(Xb, T1, T2, T3, T4, Wt1, b1, H, n);
  // layer 2: gemm + selu + fused pool -> g
  k_prop<<<pb, 256, 0, stream>>>(row_ptr, erec, perm, (const uint32*)H,  nullptr, (uint32*)T1, n, 1);
  k_prop<<<pb, 256, 0, stream>>>(row_ptr, erec, perm, (const uint32*)T1, (const uint32*)H,  (uint32*)T2, n, 2);
  k_prop<<<pb, 256, 0, stream>>>(row_ptr, erec, perm, (const uint32*)T2, (const uint32*)T1, (uint32*)T3, n, 2);
  k_prop<<<pb, 256, 0, stream>>>(row_ptr, erec, perm, (const uint32*)T3, (const uint32*)T2, (uint32*)T4, n, 2);
  k_gemm5_pool<<<gb, 256, 0, stream>>>(H, T1, T2, T3, T4, Wt2, b2, batch, g, n);
  // fc
  k_fc<<<(NG * OC + 255) / 256, 256, 0, stream>>>(g, Wfc, bfc, out, NG, OC);
}

// Round 13
// 398.738 us; speedup vs baseline: 1.8181x; 1.0651x over previous
//
#include <hip/hip_runtime.h>
#include <cstdint>

#define CH 64
#define NBLK 256          // blocks in bucket passes
#define NBMAX 1024        // max coarse buckets (n <= 131072)
#define SRCMASK 0x1FFFFu  // low 17 bits = src id

typedef __attribute__((ext_vector_type(8))) short bf16x8;
typedef __attribute__((ext_vector_type(8))) unsigned short u16x8;
typedef __attribute__((ext_vector_type(4))) float f32x4;
typedef unsigned int uint32;
typedef unsigned char uchar;

__device__ __forceinline__ unsigned short f2bf(float x) {
  unsigned u = __float_as_uint(x);
  u += 0x7FFF + ((u >> 16) & 1);          // round-to-nearest-even
  return (unsigned short)(u >> 16);
}
__device__ __forceinline__ float bflo(uint32 u) { return __uint_as_float(u << 16); }
__device__ __forceinline__ float bfhi(uint32 u) { return __uint_as_float(u & 0xFFFF0000u); }
__device__ __forceinline__ uint32 bfpack(float lo, float hi) {
  return ((uint32)f2bf(hi) << 16) | (uint32)f2bf(lo);
}

// ---------------- phase 1: per-block LDS histograms of dst>>7 and src>>7 ----------------
__global__ __launch_bounds__(256) void k_b1(const int* __restrict__ src, const int* __restrict__ dst,
                                            int* __restrict__ cntD, int* __restrict__ cntS, int E, int NB) {
  __shared__ int hD[NBMAX], hS[NBMAX];
  int t = threadIdx.x, b = blockIdx.x;
  for (int i = t; i < NBMAX; i += 256) { hD[i] = 0; hS[i] = 0; }
  __syncthreads();
  int chunk = (E + NBLK - 1) / NBLK;
  int e0 = b * chunk, e1 = min(E, e0 + chunk);
  for (int e = e0 + t; e < e1; e += 256) {
    atomicAdd(&hD[dst[e] >> 7], 1);
    atomicAdd(&hS[src[e] >> 7], 1);
  }
  __syncthreads();
  for (int i = t; i < NB; i += 256) {
    cntD[i * NBLK + b] = hD[i];
    cntS[i * NBLK + b] = hS[i];
  }
}

// ---------------- generic 2-level exclusive scan (in-place capable) ----------------
__global__ __launch_bounds__(256) void k_scan_local(const int* __restrict__ in, int* __restrict__ out,
                                                    int* __restrict__ bsum, int total) {
  __shared__ int s[256];
  int t = threadIdx.x;
  int base = blockIdx.x * 1024 + t * 4;
  int v0 = (base + 0 < total) ? in[base + 0] : 0;
  int v1 = (base + 1 < total) ? in[base + 1] : 0;
  int v2 = (base + 2 < total) ? in[base + 2] : 0;
  int v3 = (base + 3 < total) ? in[base + 3] : 0;
  int sum = v0 + v1 + v2 + v3;
  s[t] = sum;
  __syncthreads();
  for (int off = 1; off < 256; off <<= 1) {
    int x = (t >= off) ? s[t - off] : 0;
    __syncthreads();
    s[t] += x;
    __syncthreads();
  }
  int excl = s[t] - sum;
  if (base + 0 < total) out[base + 0] = excl;  excl += v0;
  if (base + 1 < total) out[base + 1] = excl;  excl += v1;
  if (base + 2 < total) out[base + 2] = excl;  excl += v2;
  if (base + 3 < total) out[base + 3] = excl;
  if (t == 255) bsum[blockIdx.x] = s[255];
}

__global__ __launch_bounds__(256) void k_scan_bsums(int* bsum, int nb) {
  __shared__ int s[256];
  int t = threadIdx.x;
  int v = (t < nb) ? bsum[t] : 0;
  s[t] = v;
  __syncthreads();
  for (int off = 1; off < 256; off <<= 1) {
    int x = (t >= off) ? s[t - off] : 0;
    __syncthreads();
    s[t] += x;
    __syncthreads();
  }
  if (t < nb) bsum[t] = s[t] - v;   // exclusive
}

__global__ __launch_bounds__(256) void k_scan_add(int* __restrict__ arr, const int* __restrict__ bsum, int total) {
  int i = blockIdx.x * 256 + threadIdx.x;
  if (i < total) arr[i] += bsum[i >> 10];
}

// ---------------- phase 2: atomic-free scatter into bucket-grouped order ----------------
// etmp record: bits 0-16 = src, bits 17-23 = dst&127 (bucket id gives the rest)
__global__ __launch_bounds__(256) void k_b2(const int* __restrict__ src, const int* __restrict__ dst,
                                            const int* __restrict__ cbaseD, const int* __restrict__ cbaseS,
                                            uint32* __restrict__ etmp, uchar* __restrict__ svals, int E, int NB) {
  __shared__ int curD[NBMAX], curS[NBMAX];
  int t = threadIdx.x, b = blockIdx.x;
  for (int i = t; i < NB; i += 256) {
    curD[i] = cbaseD[i * NBLK + b];
    curS[i] = cbaseS[i * NBLK + b];
  }
  __syncthreads();
  int chunk = (E + NBLK - 1) / NBLK;
  int e0 = b * chunk, e1 = min(E, e0 + chunk);
  for (int e = e0 + t; e < e1; e += 256) {
    int s = src[e], d = dst[e];
    int pd = atomicAdd(&curD[d >> 7], 1);
    etmp[pd] = ((uint32)(d & 127) << 17) | (uint32)s;
    int ps = atomicAdd(&curS[s >> 7], 1);
    svals[ps] = (uchar)(s & 127);
  }
}

// ---------------- phase 3a: exact out-degree per node -> neg_inv ----------------
__global__ __launch_bounds__(256) void k_b3_deg(const uchar* __restrict__ svals, const int* __restrict__ cbaseS,
                                                float* __restrict__ neg_inv, int n, int E, int NB) {
  __shared__ int h[128];
  int t = threadIdx.x, k = blockIdx.x;
  if (t < 128) h[t] = 0;
  __syncthreads();
  int lo = cbaseS[k * NBLK];
  int hi = (k + 1 < NB) ? cbaseS[(k + 1) * NBLK] : E;
  for (int e = lo + t; e < hi; e += 256) atomicAdd(&h[svals[e]], 1);
  __syncthreads();
  if (t < 128) {
    int node = k * 128 + t;
    if (node < n) {
      int c = h[t];
      neg_inv[node] = c > 0 ? (-1.0f / (float)c) : 0.0f;
    }
  }
}

// ---------------- phase 3b: per-bucket counting sort -> erec(int2) + row_ptr ----------------
__global__ __launch_bounds__(256) void k_b3_dst(const uint32* __restrict__ etmp, const int* __restrict__ cbaseD,
                                                const float* __restrict__ neg_inv, int2* __restrict__ erec,
                                                int* __restrict__ row_ptr, int n, int E, int NB) {
  __shared__ int h[128], sc[128], cur[128];
  int t = threadIdx.x, k = blockIdx.x;
  if (t < 128) h[t] = 0;
  __syncthreads();
  int lo = cbaseD[k * NBLK];
  int hi = (k + 1 < NB) ? cbaseD[(k + 1) * NBLK] : E;
  for (int e = lo + t; e < hi; e += 256) atomicAdd(&h[(etmp[e] >> 17) & 127], 1);
  __syncthreads();
  if (t < 128) sc[t] = h[t];
  __syncthreads();
  for (int off = 1; off < 128; off <<= 1) {
    int x = (t < 128 && t >= off) ? sc[t - off] : 0;
    __syncthreads();
    if (t < 128) sc[t] += x;
    __syncthreads();
  }
  if (t < 128) {
    int excl = sc[t] - h[t];
    cur[t] = excl;
    int node = k * 128 + t;
    if (node < n) row_ptr[node] = lo + excl;
  }
  if (k == NB - 1 && t == 0) row_ptr[n] = E;
  __syncthreads();
  for (int e = lo + t; e < hi; e += 256) {
    uint32 r = etmp[e];
    int s = (int)(r & SRCMASK);
    int pos = atomicAdd(&cur[(r >> 17) & 127], 1);
    erec[lo + pos] = make_int2(s, __float_as_int(neg_inv[s]));
  }
}

// ---------------- fp32 -> bf16 cast ----------------
__global__ __launch_bounds__(256) void k_cast(const float* __restrict__ x, unsigned short* __restrict__ xb,
                                              int total8) {
  int i = blockIdx.x * 256 + threadIdx.x;
  if (i < total8) {
    const float4* p = (const float4*)(x + (size_t)i * 8);
    float4 v0 = p[0], v1 = p[1];
    u16x8 w;
    w[0] = f2bf(v0.x); w[1] = f2bf(v0.y); w[2] = f2bf(v0.z); w[3] = f2bf(v0.w);
    w[4] = f2bf(v1.x); w[5] = f2bf(v1.y); w[6] = f2bf(v1.z); w[7] = f2bf(v1.w);
    *(u16x8*)(xb + (size_t)i * 8) = w;
  }
}

// ---------------- sparse propagation: HALF-WAVE per node, int2 erec (R10 design) ----------------
__global__ __launch_bounds__(256) void k_prop(const int* __restrict__ row_ptr, const int2* __restrict__ erec,
                                              const uint32* __restrict__ t_in,
                                              const uint32* __restrict__ t_sub,
                                              uint32* __restrict__ t_out, int n, int mode) {
  int tid = threadIdx.x;
  int lane = tid & 63;
  int cp = lane & 31;                    // channel pair: channels 2cp, 2cp+1
  int h = lane >> 5;                     // half id -> which node
  int node = blockIdx.x * 8 + ((tid >> 6) << 1) + h;
  bool active = node < n;
  int beg = active ? row_ptr[node] : 0;
  int end = active ? row_ptr[node + 1] : 0;
  float a0 = 0.f, a1 = 0.f, b0 = 0.f, b1 = 0.f, c0 = 0.f, c1 = 0.f, d0 = 0.f, d1 = 0.f;
  float e0a = 0.f, e1a = 0.f, f0 = 0.f, f1 = 0.f, g0 = 0.f, g1 = 0.f, h0 = 0.f, h1 = 0.f;
  int e = beg;
  for (; e + 8 <= end; e += 8) {
    int2 q0 = erec[e + 0]; int2 q1 = erec[e + 1]; int2 q2 = erec[e + 2]; int2 q3 = erec[e + 3];
    int2 q4 = erec[e + 4]; int2 q5 = erec[e + 5]; int2 q6 = erec[e + 6]; int2 q7 = erec[e + 7];
    uint32 u0 = t_in[q0.x * 32 + cp];
    uint32 u1 = t_in[q1.x * 32 + cp];
    uint32 u2 = t_in[q2.x * 32 + cp];
    uint32 u3 = t_in[q3.x * 32 + cp];
    uint32 u4 = t_in[q4.x * 32 + cp];
    uint32 u5 = t_in[q5.x * 32 + cp];
    uint32 u6 = t_in[q6.x * 32 + cp];
    uint32 u7 = t_in[q7.x * 32 + cp];
    float w0 = __int_as_float(q0.y), w1 = __int_as_float(q1.y);
    float w2 = __int_as_float(q2.y), w3 = __int_as_float(q3.y);
    float w4 = __int_as_float(q4.y), w5 = __int_as_float(q5.y);
    float w6 = __int_as_float(q6.y), w7 = __int_as_float(q7.y);
    a0 = fmaf(w0, bflo(u0), a0);   a1 = fmaf(w0, bfhi(u0), a1);
    b0 = fmaf(w1, bflo(u1), b0);   b1 = fmaf(w1, bfhi(u1), b1);
    c0 = fmaf(w2, bflo(u2), c0);   c1 = fmaf(w2, bfhi(u2), c1);
    d0 = fmaf(w3, bflo(u3), d0);   d1 = fmaf(w3, bfhi(u3), d1);
    e0a = fmaf(w4, bflo(u4), e0a); e1a = fmaf(w4, bfhi(u4), e1a);
    f0 = fmaf(w5, bflo(u5), f0);   f1 = fmaf(w5, bfhi(u5), f1);
    g0 = fmaf(w6, bflo(u6), g0);   g1 = fmaf(w6, bfhi(u6), g1);
    h0 = fmaf(w7, bflo(u7), h0);   h1 = fmaf(w7, bfhi(u7), h1);
  }
  if (e + 4 <= end) {
    int2 q0 = erec[e + 0]; int2 q1 = erec[e + 1]; int2 q2 = erec[e + 2]; int2 q3 = erec[e + 3];
    uint32 u0 = t_in[q0.x * 32 + cp];
    uint32 u1 = t_in[q1.x * 32 + cp];
    uint32 u2 = t_in[q2.x * 32 + cp];
    uint32 u3 = t_in[q3.x * 32 + cp];
    float w0 = __int_as_float(q0.y), w1 = __int_as_float(q1.y);
    float w2 = __int_as_float(q2.y), w3 = __int_as_float(q3.y);
    a0 = fmaf(w0, bflo(u0), a0);   a1 = fmaf(w0, bfhi(u0), a1);
    b0 = fmaf(w1, bflo(u1), b0);   b1 = fmaf(w1, bfhi(u1), b1);
    c0 = fmaf(w2, bflo(u2), c0);   c1 = fmaf(w2, bfhi(u2), c1);
    d0 = fmaf(w3, bflo(u3), d0);   d1 = fmaf(w3, bfhi(u3), d1);
    e += 4;
  }
  if (e + 2 <= end) {
    int2 q0 = erec[e + 0]; int2 q1 = erec[e + 1];
    uint32 u0 = t_in[q0.x * 32 + cp];
    uint32 u1 = t_in[q1.x * 32 + cp];
    float w0 = __int_as_float(q0.y), w1 = __int_as_float(q1.y);
    a0 = fmaf(w0, bflo(u0), a0);   a1 = fmaf(w0, bfhi(u0), a1);
    b0 = fmaf(w1, bflo(u1), b0);   b1 = fmaf(w1, bfhi(u1), b1);
    e += 2;
  }
  if (e < end) {
    int2 q = erec[e];
    uint32 u = t_in[q.x * 32 + cp];
    float w = __int_as_float(q.y);
    a0 = fmaf(w, bflo(u), a0);
    a1 = fmaf(w, bfhi(u), a1);
  }
  float s0 = ((a0 + b0) + (c0 + d0)) + ((e0a + f0) + (g0 + h0));
  float s1 = ((a1 + b1) + (c1 + d1)) + ((e1a + f1) + (g1 + h1));
  if (active) {
    if (mode == 2) {
      uint32 u = t_sub[(size_t)node * 32 + cp];
      s0 = 2.0f * s0 - bflo(u);
      s1 = 2.0f * s1 - bfhi(u);
    }
    t_out[(size_t)node * 32 + cp] = bfpack(s0, s1);
  }
}

// ---------------- W transpose + bf16 convert: Wt[j*320 + k] = bf16(W[k*64 + j]) ----------------
__global__ __launch_bounds__(256) void k_prepW(const float* __restrict__ W, unsigned short* __restrict__ Wt) {
  int o = blockIdx.x * 256 + threadIdx.x;  // o = j*320 + k
  if (o < 64 * 320) {
    int j = o / 320, k = o - j * 320;
    Wt[o] = f2bf(W[k * 64 + j]);
  }
}

__device__ __forceinline__ float selu(float v) {
  const float sc = 1.0507009873554805f, al = 1.6732632423543773f;
  return (v > 0.f) ? (sc * v) : (sc * al * (expf(v) - 1.f));
}

// ---------------- layer-1 gemm v3: B-in-registers, grid-stride strips, double-buffered LDS ----------------
// Per wave: 10 loop-invariant Wt fragments in VGPRs (no global loads in the strip loop).
// 2x20KB LDS double buffer: stage(strip i+1) overlaps compute(strip i); 1 barrier/strip.
__global__ __launch_bounds__(256) void k_gemm5(
    const unsigned short* __restrict__ M0, const unsigned short* __restrict__ M1,
    const unsigned short* __restrict__ M2, const unsigned short* __restrict__ M3,
    const unsigned short* __restrict__ M4,
    const unsigned short* __restrict__ Wt, const float* __restrict__ bias,
    unsigned short* __restrict__ outp, int n, int nstrips) {
  __shared__ unsigned short lds[2][32 * 320];   // 40 KB
  const int t = threadIdx.x;
  const int lane = t & 63, wave = t >> 6;
  const int g = lane >> 4, r16 = lane & 15;
  const unsigned short* mats[5] = {M0, M1, M2, M3, M4};
  const int colB = wave * 16 + r16;
  bf16x8 Bf[10];
#pragma unroll
  for (int kk = 0; kk < 10; ++kk)
    Bf[kk] = *(const bf16x8*)(Wt + colB * 320 + kk * 32 + g * 8);
  const float bv = bias[colB];
  const int srow = t >> 3, scc = t & 7;         // staging: row 0..31, 16B chunk 0..7

  int strip = blockIdx.x;
  if (strip >= nstrips) return;
  int cur = 0;
  {  // stage first strip -> buf 0
    int node0 = strip * 32;
#pragma unroll
    for (int m = 0; m < 5; ++m) {
      int ca = m * 8 + scc;
      u16x8 w = {};
      if (node0 + srow < n)
        w = *(const u16x8*)(mats[m] + (size_t)(node0 + srow) * CH + scc * 8);
      *(u16x8*)(&lds[0][srow * 320 + ((ca ^ (srow & 7)) << 3)]) = w;
    }
  }
  __syncthreads();
  for (; strip < nstrips; strip += gridDim.x) {
    int nxt = strip + gridDim.x;
    if (nxt < nstrips) {                        // stage next strip -> other buf
      int node0 = nxt * 32;
#pragma unroll
      for (int m = 0; m < 5; ++m) {
        int ca = m * 8 + scc;
        u16x8 w = {};
        if (node0 + srow < n)
          w = *(const u16x8*)(mats[m] + (size_t)(node0 + srow) * CH + scc * 8);
        *(u16x8*)(&lds[cur ^ 1][srow * 320 + ((ca ^ (srow & 7)) << 3)]) = w;
      }
    }
    const unsigned short* L = lds[cur];
    const int rowA0 = r16, rowA1 = r16 + 16;
    f32x4 acc0 = {}, acc1 = {};
#pragma unroll
    for (int kk = 0; kk < 10; ++kk) {
      int ca = kk * 4 + g;
      bf16x8 a0 = *(const bf16x8*)(&L[rowA0 * 320 + ((ca ^ (rowA0 & 7)) << 3)]);
      bf16x8 a1 = *(const bf16x8*)(&L[rowA1 * 320 + ((ca ^ (rowA1 & 7)) << 3)]);
      acc0 = __builtin_amdgcn_mfma_f32_16x16x32_bf16(a0, Bf[kk], acc0, 0, 0, 0);
      acc1 = __builtin_amdgcn_mfma_f32_16x16x32_bf16(a1, Bf[kk], acc1, 0, 0, 0);
    }
    int node0 = strip * 32;
    const f32x4 accs[2] = {acc0, acc1};
#pragma unroll
    for (int i = 0; i < 2; ++i) {
#pragma unroll
      for (int rr = 0; rr < 4; ++rr) {
        int row = node0 + i * 16 + g * 4 + rr;
        if (row < n)
          outp[(size_t)row * CH + colB] = f2bf(selu(accs[i][rr] + bv));
      }
    }
    __syncthreads();   // stage(nxt) done + lds[cur] reads done
    cur ^= 1;
  }
}

// ---------------- layer-2 gemm v3 + selu + FUSED global_add_pool ----------------
__global__ __launch_bounds__(256) void k_gemm5_pool(
    const unsigned short* __restrict__ M0, const unsigned short* __restrict__ M1,
    const unsigned short* __restrict__ M2, const unsigned short* __restrict__ M3,
    const unsigned short* __restrict__ M4,
    const unsigned short* __restrict__ Wt, const float* __restrict__ bias,
    const int* __restrict__ batch, float* __restrict__ gout, int n, int nstrips) {
  __shared__ unsigned short lds[2][32 * 320];   // 40 KB; S tile reuses lds[cur]
  const int t = threadIdx.x;
  const int lane = t & 63, wave = t >> 6;
  const int g = lane >> 4, r16 = lane & 15;
  const unsigned short* mats[5] = {M0, M1, M2, M3, M4};
  const int colB = wave * 16 + r16;
  bf16x8 Bf[10];
#pragma unroll
  for (int kk = 0; kk < 10; ++kk)
    Bf[kk] = *(const bf16x8*)(Wt + colB * 320 + kk * 32 + g * 8);
  const float bv = bias[colB];
  const int srow = t >> 3, scc = t & 7;

  int strip = blockIdx.x;
  if (strip >= nstrips) return;
  int cur = 0;
  {
    int node0 = strip * 32;
#pragma unroll
    for (int m = 0; m < 5; ++m) {
      int ca = m * 8 + scc;
      u16x8 w = {};
      if (node0 + srow < n)
        w = *(const u16x8*)(mats[m] + (size_t)(node0 + srow) * CH + scc * 8);
      *(u16x8*)(&lds[0][srow * 320 + ((ca ^ (srow & 7)) << 3)]) = w;
    }
  }
  __syncthreads();
  for (; strip < nstrips; strip += gridDim.x) {
    int nxt = strip + gridDim.x;
    if (nxt < nstrips) {
      int node0 = nxt * 32;
#pragma unroll
      for (int m = 0; m < 5; ++m) {
        int ca = m * 8 + scc;
        u16x8 w = {};
        if (node0 + srow < n)
          w = *(const u16x8*)(mats[m] + (size_t)(node0 + srow) * CH + scc * 8);
        *(u16x8*)(&lds[cur ^ 1][srow * 320 + ((ca ^ (srow & 7)) << 3)]) = w;
      }
    }
    const unsigned short* L = lds[cur];
    const int rowA0 = r16, rowA1 = r16 + 16;
    f32x4 acc0 = {}, acc1 = {};
#pragma unroll
    for (int kk = 0; kk < 10; ++kk) {
      int ca = kk * 4 + g;
      bf16x8 a0 = *(const bf16x8*)(&L[rowA0 * 320 + ((ca ^ (rowA0 & 7)) << 3)]);
      bf16x8 a1 = *(const bf16x8*)(&L[rowA1 * 320 + ((ca ^ (rowA1 & 7)) << 3)]);
      acc0 = __builtin_amdgcn_mfma_f32_16x16x32_bf16(a0, Bf[kk], acc0, 0, 0, 0);
      acc1 = __builtin_amdgcn_mfma_f32_16x16x32_bf16(a1, Bf[kk], acc1, 0, 0, 0);
    }
    __syncthreads();                    // all lds[cur] reads done; stage(nxt) done
    float* S = (float*)lds[cur];        // [32][65] = 8.3 KB
    const f32x4 accs[2] = {acc0, acc1};
#pragma unroll
    for (int i = 0; i < 2; ++i)
#pragma unroll
      for (int rr = 0; rr < 4; ++rr) {
        int row = i * 16 + g * 4 + rr;
        S[row * 65 + colB] = selu(accs[i][rr] + bv);
      }
    __syncthreads();
    // pool: wave w owns rows w*8..w*8+7 (sorted batch -> run-length + atomic flush)
    int node0 = strip * 32;
    int c = t & 63, w = t >> 6;
    float curv = 0.f;
    int curg = -1;
    for (int r = 0; r < 8; ++r) {
      int row = w * 8 + r;
      int gn = node0 + row;
      if (gn >= n) break;
      int b = batch[gn];
      if (b != curg) {
        if (curg >= 0) atomicAdd(&gout[curg * CH + c], curv);
        curg = b;
        curv = 0.f;
      }
      curv += S[row * 65 + c];
    }
    if (curg >= 0) atomicAdd(&gout[curg * CH + c], curv);
    __syncthreads();   // pool reads done before next iteration stages into this buf
    cur ^= 1;
  }
}

__global__ __launch_bounds__(256) void k_fc(const float* __restrict__ g, const float* __restrict__ Wfc,
                                            const float* __restrict__ bfc, float* __restrict__ outp,
                                            int ng, int oc) {
  int i = blockIdx.x * 256 + threadIdx.x;
  if (i < ng * oc) {
    int gi = i / oc, o = i - gi * oc;
    float s = bfc[o];
    for (int ci = 0; ci < CH; ++ci) s += g[gi * CH + ci] * Wfc[ci * oc + o];
    outp[i] = s;
  }
}

extern "C" void kernel_launch(void* const* d_in, const int* in_sizes, int n_in,
                              void* d_out, int out_size, void* d_ws, size_t ws_size,
                              hipStream_t stream) {
  const float* x   = (const float*)d_in[0];
  const int* eidx  = (const int*)d_in[1];
  const int* batch = (const int*)d_in[2];
  const float* W1  = (const float*)d_in[3];
  const float* b1  = (const float*)d_in[4];
  const float* W2  = (const float*)d_in[5];
  const float* b2  = (const float*)d_in[6];
  const float* Wfc = (const float*)d_in[7];
  const float* bfc = (const float*)d_in[8];
  float* out = (float*)d_out;

  const int n  = in_sizes[0] / CH;        // 100000
  const int E  = in_sizes[1] / 2;         // 1250000
  const int OC = in_sizes[8];             // 10
  const int NG = out_size / OC;           // 64
  const int NB = (n + 127) >> 7;          // 782 coarse buckets

  const int* src = eidx;
  const int* dst = eidx + E;

  size_t off = 0;
  char* base = (char*)d_ws;
  auto alloc = [&](size_t bytes) -> void* {
    size_t cur = (off + 255) & ~(size_t)255;
    off = cur + bytes;
    return (void*)(base + cur);
  };
  const int scan_total = NB * NBLK;                  // 200192
  const int scan_nb    = (scan_total + 1023) / 1024; // 196
  int*   cntD   = (int*)alloc((size_t)scan_total * 4);
  int*   cntS   = (int*)alloc((size_t)scan_total * 4);
  int*   bsumD  = (int*)alloc((size_t)scan_nb * 4);
  int*   bsumS  = (int*)alloc((size_t)scan_nb * 4);
  float* neg_inv = (float*)alloc((size_t)n * 4);
  int*   row_ptr = (int*)alloc((size_t)(n + 1) * 4);
  int2*  erec    = (int2*)alloc((size_t)E * 8);
  const size_t tb16 = (size_t)n * CH * 2;
  unsigned short* Xb = (unsigned short*)alloc(tb16);
  unsigned short* T1 = (unsigned short*)alloc(tb16);
  unsigned short* T2 = (unsigned short*)alloc(tb16);
  unsigned short* T3 = (unsigned short*)alloc(tb16);
  unsigned short* T4 = (unsigned short*)alloc(tb16);
  unsigned short* H  = (unsigned short*)alloc(tb16);
  uint32* etmp  = (uint32*)alloc((size_t)E * 4);
  uchar*  svals = (uchar*)alloc((size_t)E);
  float* g  = (float*)alloc((size_t)NG * CH * 4);
  unsigned short* Wt1 = (unsigned short*)alloc(64 * 320 * 2);
  unsigned short* Wt2 = (unsigned short*)alloc(64 * 320 * 2);
  if (off > ws_size) return;  // workspace too small -> fail loudly (zeros out)

  hipMemsetAsync(g, 0, (size_t)NG * CH * 4, stream);

  // ---- atomic-free CSR build ----
  k_b1<<<NBLK, 256, 0, stream>>>(src, dst, cntD, cntS, E, NB);
  k_scan_local<<<scan_nb, 256, 0, stream>>>(cntD, cntD, bsumD, scan_total);
  k_scan_bsums<<<1, 256, 0, stream>>>(bsumD, scan_nb);
  k_scan_add<<<(scan_total + 255) / 256, 256, 0, stream>>>(cntD, bsumD, scan_total);
  k_scan_local<<<scan_nb, 256, 0, stream>>>(cntS, cntS, bsumS, scan_total);
  k_scan_bsums<<<1, 256, 0, stream>>>(bsumS, scan_nb);
  k_scan_add<<<(scan_total + 255) / 256, 256, 0, stream>>>(cntS, bsumS, scan_total);
  k_b2<<<NBLK, 256, 0, stream>>>(src, dst, cntD, cntS, etmp, svals, E, NB);
  k_b3_deg<<<NB, 256, 0, stream>>>(svals, cntS, neg_inv, n, E, NB);
  k_b3_dst<<<NB, 256, 0, stream>>>(etmp, cntD, neg_inv, erec, row_ptr, n, E, NB);

  k_prepW<<<80, 256, 0, stream>>>(W1, Wt1);
  k_prepW<<<80, 256, 0, stream>>>(W2, Wt2);
  k_cast<<<(n * CH / 8 + 255) / 256, 256, 0, stream>>>(x, Xb, n * CH / 8);

  const int pb = (n + 7) / 8;
  const int nstrips = (n + 31) / 32;
  const int gb = nstrips < 1024 ? nstrips : 1024;   // 4 blocks/CU at 40KB LDS
  // layer 1
  k_prop<<<pb, 256, 0, stream>>>(row_ptr, erec, (const uint32*)Xb, nullptr, (uint32*)T1, n, 1);
  k_prop<<<pb, 256, 0, stream>>>(row_ptr, erec, (const uint32*)T1, (const uint32*)Xb, (uint32*)T2, n, 2);
  k_prop<<<pb, 256, 0, stream>>>(row_ptr, erec, (const uint32*)T2, (const uint32*)T1, (uint32*)T3, n, 2);
  k_prop<<<pb, 256, 0, stream>>>(row_ptr, erec, (const uint32*)T3, (const uint32*)T2, (uint32*)T4, n, 2);
  k_gemm5<<<gb, 256, 0, stream>>>(Xb, T1, T2, T3, T4, Wt1, b1, H, n, nstrips);
  // layer 2: gemm + selu + fused pool -> g
  k_prop<<<pb, 256, 0, stream>>>(row_ptr, erec, (const uint32*)H,  nullptr, (uint32*)T1, n, 1);
  k_prop<<<pb, 256, 0, stream>>>(row_ptr, erec, (const uint32*)T1, (const uint32*)H,  (uint32*)T2, n, 2);
  k_prop<<<pb, 256, 0, stream>>>(row_ptr, erec, (const uint32*)T2, (const uint32*)T1, (uint32*)T3, n, 2);
  k_prop<<<pb, 256, 0, stream>>>(row_ptr, erec, (const uint32*)T3, (const uint32*)T2, (uint32*)T4, n, 2);
  k_gemm5_pool<<<gb, 256, 0, stream>>>(H, T1, T2, T3, T4, Wt2, b2, batch, g, n, nstrips);
  // fc
  k_fc<<<(NG * OC + 255) / 256, 256, 0, stream>>>(g, Wfc, bfc, out, NG, OC);
}